// Round 11
// baseline (787.852 us; speedup 1.0000x reference)
//
#include <hip/hip_runtime.h>
#include <stdint.h>

#define NN 131008      // real node count
#define NPAD 131072    // padded to 1024 * 128
#define EE 262016
#define HD 256
#define GG 64
#define TT 2047

typedef __attribute__((ext_vector_type(8))) short bfrag;
typedef __attribute__((ext_vector_type(4))) float f32x4;

__device__ __forceinline__ float bflo(unsigned u){ union{unsigned i; float f;} v; v.i = u<<16; return v.f; }
__device__ __forceinline__ float bfhi(unsigned u){ union{unsigned i; float f;} v; v.i = u & 0xffff0000u; return v.f; }
__device__ __forceinline__ unsigned short f2bf(float f){
  union{unsigned i; float fl;} v; v.fl = f; unsigned i = v.i;
  return (unsigned short)((i + 0x7fffu + ((i>>16)&1u)) >> 16);
}
__device__ __forceinline__ unsigned pack2(float a, float b){
  return (unsigned)f2bf(a) | ((unsigned)f2bf(b)<<16);
}
// HW packed f32->bf16 RNE (identical rounding to f2bf; 1 op per pair vs ~11)
__device__ __forceinline__ unsigned cvtpk(float a, float b){
  unsigned r; asm("v_cvt_pk_bf16_f32 %0, %1, %2" : "=v"(r) : "v"(a), "v"(b)); return r;
}
__device__ __forceinline__ float bfel(short s){
  union{unsigned i; float f;} v; v.i = ((unsigned)(unsigned short)s) << 16; return v.f;
}
__device__ __forceinline__ void gload16(const void* g, void* s){
  __builtin_amdgcn_global_load_lds((__attribute__((address_space(1))) void*)g,
                                   (__attribute__((address_space(3))) void*)s, 16, 0, 0);
}

// bn+relu on 8 bf16 values; rounds back to bf16 via cvt_pk pairs
__device__ __forceinline__ bfrag bnrelu8(bfrag t, float4 a0, float4 a1, float4 c0, float4 c1){
  unsigned u0 = cvtpk(fmaxf(a0.x*bfel(t[0])+c0.x,0.f), fmaxf(a0.y*bfel(t[1])+c0.y,0.f));
  unsigned u1 = cvtpk(fmaxf(a0.z*bfel(t[2])+c0.z,0.f), fmaxf(a0.w*bfel(t[3])+c0.w,0.f));
  unsigned u2 = cvtpk(fmaxf(a1.x*bfel(t[4])+c1.x,0.f), fmaxf(a1.y*bfel(t[5])+c1.y,0.f));
  unsigned u3 = cvtpk(fmaxf(a1.z*bfel(t[6])+c1.z,0.f), fmaxf(a1.w*bfel(t[7])+c1.w,0.f));
  union{ unsigned u[4]; bfrag b; } r;
  r.u[0]=u0; r.u[1]=u1; r.u[2]=u2; r.u[3]=u3;
  return r.b;
}

// atomic add of two bf16 values at a 4B-aligned pair address (rootsum only)
__device__ __forceinline__ void atomic_add_bf16x2(unsigned short* p, float a, float b){
#if __has_builtin(__builtin_amdgcn_global_atomic_fadd_v2bf16)
  typedef __attribute__((ext_vector_type(2))) short s16x2;
  s16x2 v; v.x = (short)f2bf(a); v.y = (short)f2bf(b);
  __builtin_amdgcn_global_atomic_fadd_v2bf16((__attribute__((address_space(1))) s16x2*)p, v);
#else
  unsigned* up = (unsigned*)p;
  unsigned old = *up, assumed;
  do {
    assumed = old;
    unsigned nv = pack2(bflo(assumed) + a, bfhi(assumed) + b);
    old = atomicCAS(up, assumed, nv);
  } while (old != assumed);
#endif
}

// ---- prep: convw (blocks 0..2047) | embed (2048..18431) | hist (18432..19455) ----
__global__ void k_prep(const float* __restrict__ W1, const float* __restrict__ W2,
                       unsigned short* __restrict__ wbf,
                       const int* __restrict__ x, const float* __restrict__ en,
                       const float* __restrict__ el, unsigned short* __restrict__ hbf,
                       const int* __restrict__ ed, int* __restrict__ deg){
  int b = blockIdx.x;
  if (b < 2048){                    // convw: 524288 floats -> bf16
    int idx = b*256 + threadIdx.x;
    float v = (idx < 262144) ? W1[idx] : W2[idx - 262144];
    wbf[idx] = f2bf(v);
  } else if (b < 18432){            // embed: 8 cols/thread
    size_t i8 = ((size_t)(b - 2048)*256 + threadIdx.x) << 3;
    int row = (int)(i8 >> 8); int k = (int)(i8 & 255);
    uint4 o;
    if (row < NN){
      const float* src = (k < 128) ? en + (size_t)x[2*row]*128 + k
                                   : el + (size_t)x[2*row+1]*128 + (k-128);
      float4 v0 = *(const float4*)src;
      float4 v1 = *(const float4*)(src + 4);
      o.x = cvtpk(v0.x, v0.y); o.y = cvtpk(v0.z, v0.w);
      o.z = cvtpk(v1.x, v1.y); o.w = cvtpk(v1.z, v1.w);
    } else { o.x = o.y = o.z = o.w = 0u; }
    *(uint4*)(hbf + i8) = o;
  } else {                          // hist
    int e = (b - 18432)*256 + threadIdx.x;
    if (e < EE) atomicAdd(&deg[ed[e]], 1);
  }
}

// ======== CSR build (edges fixed; rebuilt every launch) ========
__global__ void k_scan_block(const int* __restrict__ deg, int* __restrict__ start,
                             int* __restrict__ bsum){
  __shared__ int sh[256];
  int t = threadIdx.x;
  int i = blockIdx.x*256 + t;
  int v = deg[i];
  int val = v; sh[t] = val; __syncthreads();
  for (int off = 1; off < 256; off <<= 1){
    int add = (t >= off) ? sh[t-off] : 0;
    __syncthreads();
    val += add; sh[t] = val;
    __syncthreads();
  }
  start[i] = val - v;
  if (t == 255) bsum[blockIdx.x] = val;
}
__global__ void k_scan_top(int* __restrict__ bsum){
  __shared__ int sh[512];
  int t = threadIdx.x;            // 512 threads
  int v = bsum[t];
  int val = v; sh[t] = val; __syncthreads();
  for (int off = 1; off < 512; off <<= 1){
    int add = (t >= off) ? sh[t-off] : 0;
    __syncthreads();
    val += add; sh[t] = val;
    __syncthreads();
  }
  bsum[t] = val - v;
}
__global__ void k_fill(const int* __restrict__ es, const int* __restrict__ ed,
                       const float* __restrict__ ew, const int* __restrict__ start,
                       const int* __restrict__ bsum,
                       int* __restrict__ cursor0, uint2* __restrict__ pairs){
  int e = blockIdx.x*256 + threadIdx.x;
  if (e < EE){
    int d = ed[e];
    int pos = start[d] + bsum[d >> 8] + atomicAdd(&cursor0[d], 1);
    uint2 p; p.x = (unsigned)es[e];
    union{float f; unsigned u;} w; w.f = ew[e];
    p.y = w.u;
    pairs[pos] = p;
  }
}

// ---- gather: m[r] = h[r] + sum_{e:dst=r} w_e*h[src_e] ----
// 32 lanes/row x 8 cols (uint4); 8 rows/block; edge loop unrolled x2 so the two
// dependent load chains (pairs -> h[src]) overlap.
__global__ void k_gather(const int* __restrict__ deg, const int* __restrict__ start,
                         const int* __restrict__ bsum,
                         const uint2* __restrict__ pairs,
                         const unsigned short* __restrict__ hbf,
                         unsigned short* __restrict__ mbf){
  int half = threadIdx.x >> 5, lane32 = threadIdx.x & 31;
  int row = blockIdx.x*8 + half;
  size_t base = (size_t)row*HD + (lane32 << 3);
  uint4 o;
  if (row < NN){
    uint4 hv = *(const uint4*)(hbf + base);
    float a0 = bflo(hv.x), a1 = bfhi(hv.x), a2 = bflo(hv.y), a3 = bfhi(hv.y);
    float a4 = bflo(hv.z), a5 = bfhi(hv.z), a6 = bflo(hv.w), a7 = bfhi(hv.w);
    int d = deg[row], s = start[row] + bsum[row >> 8];
    int j = 0;
    for (; j + 2 <= d; j += 2){
      uint2 p0 = pairs[s + j];
      uint2 p1 = pairs[s + j + 1];
      union{unsigned u; float f;} w0; w0.u = p0.y;
      union{unsigned u; float f;} w1; w1.u = p1.y;
      uint4 s0 = *(const uint4*)(hbf + (size_t)p0.x*HD + (lane32 << 3));
      uint4 s1 = *(const uint4*)(hbf + (size_t)p1.x*HD + (lane32 << 3));
      a0 += bflo(s0.x)*w0.f + bflo(s1.x)*w1.f; a1 += bfhi(s0.x)*w0.f + bfhi(s1.x)*w1.f;
      a2 += bflo(s0.y)*w0.f + bflo(s1.y)*w1.f; a3 += bfhi(s0.y)*w0.f + bfhi(s1.y)*w1.f;
      a4 += bflo(s0.z)*w0.f + bflo(s1.z)*w1.f; a5 += bfhi(s0.z)*w0.f + bfhi(s1.z)*w1.f;
      a6 += bflo(s0.w)*w0.f + bflo(s1.w)*w1.f; a7 += bfhi(s0.w)*w0.f + bfhi(s1.w)*w1.f;
    }
    if (j < d){
      uint2 pr = pairs[s + j];
      union{unsigned u; float f;} wg; wg.u = pr.y;
      uint4 sv = *(const uint4*)(hbf + (size_t)pr.x*HD + (lane32 << 3));
      a0 += bflo(sv.x)*wg.f; a1 += bfhi(sv.x)*wg.f;
      a2 += bflo(sv.y)*wg.f; a3 += bfhi(sv.y)*wg.f;
      a4 += bflo(sv.z)*wg.f; a5 += bfhi(sv.z)*wg.f;
      a6 += bflo(sv.w)*wg.f; a7 += bfhi(sv.w)*wg.f;
    }
    o.x = cvtpk(a0, a1); o.y = cvtpk(a2, a3);
    o.z = cvtpk(a4, a5); o.w = cvtpk(a6, a7);
  } else { o.x = o.y = o.z = o.w = 0u; }
  *(uint4*)(mbf + base) = o;
}

// ---- last layer: m[root_g] += sum of h over graph g's 2047 contiguous rows ----
__global__ void k_rootsum(const unsigned short* __restrict__ hbf, unsigned short* __restrict__ m){
  int g = blockIdx.x >> 4, ch = blockIdx.x & 15;
  int col = threadIdx.x * 2;
  int nr = (ch == 15) ? 127 : 128;
  const unsigned short* p = hbf + ((size_t)g*TT + ch*128)*HD + col;
  float a = 0.f, b = 0.f;
  for (int r = 0; r < nr; ++r){
    unsigned u = *(const unsigned*)(p + (size_t)r*HD);
    a += bflo(u); b += bfhi(u);
  }
  atomic_add_bf16x2(m + (size_t)g*TT*HD + col, a, b);
}

// ======== Persistent GEMM, N-split for 2 blocks/CU (round-22) ========
// R10 PMC: gemm 41us at Occupancy 16.7%, MfmaUtil 15%, HBM 30% -- latency-bound
// at 1 block/CU (128KB resident B caps residency; nothing hides A-ring latency
// + prologue/epilogue drains). Split N into 2 halves: B-half = 64KB -> LDS
// 68KB/block -> 2 blocks/CU (16 waves), one block's stalls overlap the other's
// MFMA. Grid 512: mg=bid>>1 owns 512 rows, nh=bid&1 owns 128 cols. A read 2x
// total but t/mbf are freshly-written L3 residents. Wave tile 32x64:
// acc[2][4], 4 B-ds_reads + 8 MFMA per step.
template<bool TRANS>
__device__ __forceinline__ void gemm_body(const unsigned short* __restrict__ A,
                                          const unsigned short* __restrict__ B,
                                          unsigned short* __restrict__ C,
                                          float* __restrict__ gsum, float* __restrict__ gsq,
                                          const float* __restrict__ sum1,
                                          const float* __restrict__ sq1,
                                          const float* __restrict__ g1v,
                                          const float* __restrict__ be1v){
  __shared__ unsigned short Bs[32768];      // 64 KB: 4 kt-blocks of [128][64], XOR-swizzled
  __shared__ float st[512];                 // end-of-block stat scratch (256 used + pad)
  __shared__ float acf[256];                // gemm2 BN coefs (a)
  __shared__ float ccf[256];                // gemm2 BN coefs (c)
  const int tid = threadIdx.x, lane = tid & 63, w = tid >> 6;   // 8 waves
  const int wr = w >> 1, wc = w & 1;        // 4 x 2 wave grid; wave tile 32x64
  const int bid = blockIdx.x;               // 0..511
  const int nh = bid & 1, mg = bid >> 1;    // N-half, M-group
  const int q = lane >> 4, r15 = lane & 15, r7 = lane & 7;

  if (TRANS && tid < 256){
    const float inv_n = 1.f/(float)NN;
    float mean = sum1[tid] * inv_n;
    float var  = fmaxf(sq1[tid] * inv_n - mean*mean, 0.f);
    float aj   = g1v[tid] * rsqrtf(var + 1e-5f);
    acf[tid] = aj;
    ccf[tid] = be1v[tid] - aj*mean;
  }
  st[tid < 512 ? tid : 0] = 0.f;

  // stage this block's B half once (8 DMAs/thread): rows nh*128..nh*128+127
#pragma unroll
  for (int kt = 0; kt < 4; ++kt)
#pragma unroll
    for (int it = 0; it < 2; ++it){
      int ci = it*512 + tid;
      int row = ci >> 3, cp = ci & 7;
      int cl = cp ^ (row & 7);
      gload16(B + (size_t)(nh*128 + row)*HD + kt*64 + cl*8, &Bs[kt*8192 + ci*8]);
    }

  // A register ring, depth 4 (slots s&3; prefetch distance 3)
  bfrag rA[4][2];
  auto aload = [&](int s, int slot){
    const int t2 = mg*4 + (s >> 3), ks = s & 7;
    const unsigned short* p = A + ((size_t)(t2*128 + wr*32 + r15))*HD + ks*32 + (q << 3);
    rA[slot][0] = *(const bfrag*)p;
    rA[slot][1] = *(const bfrag*)(p + 16*HD);
  };
  aload(0, 0); aload(1, 1); aload(2, 2);

  asm volatile("s_waitcnt vmcnt(0) lgkmcnt(0)" ::: "memory");
  __builtin_amdgcn_s_barrier();             // the ONLY block barrier before the reduce

  f32x4 acc[2][4];
  f32x4 zz = {0.f, 0.f, 0.f, 0.f};
#pragma unroll
  for (int a = 0; a < 2; ++a)
#pragma unroll
    for (int c = 0; c < 4; ++c) acc[a][c] = zz;
  float cs[4] = {0,0,0,0}, cq[4] = {0,0,0,0};

#pragma unroll 4
  for (int s = 0; s < 32; ++s){
    if (s < 29) aload(s + 3, (s + 3) & 3);  // per-wave prefetch, distance 3

    bfrag a0 = rA[s & 3][0], a1 = rA[s & 3][1];
    const int ks = s & 7;
    if (TRANS){
      const int kb = ks*32 + (q << 3);
      float4 ca0 = *(const float4*)&acf[kb];
      float4 ca1 = *(const float4*)&acf[kb + 4];
      float4 cc0 = *(const float4*)&ccf[kb];
      float4 cc1 = *(const float4*)&ccf[kb + 4];
      a0 = bnrelu8(a0, ca0, ca1, cc0, cc1);
      a1 = bnrelu8(a1, ca0, ca1, cc0, cc1);
    }

    const int kt64 = ks >> 1, hf = ks & 1;
    bfrag bf[4];
#pragma unroll
    for (int ct = 0; ct < 4; ++ct){
      int rb = wc*64 + ct*16 + r15;
      bf[ct] = *(const bfrag*)&Bs[kt64*8192 + rb*64 + (((q + 4*hf) ^ r7) << 3)];
    }
    __builtin_amdgcn_s_setprio(1);
#pragma unroll
    for (int ct = 0; ct < 4; ++ct){
      acc[0][ct] = __builtin_amdgcn_mfma_f32_16x16x32_bf16(a0, bf[ct], acc[0][ct], 0, 0, 0);
      acc[1][ct] = __builtin_amdgcn_mfma_f32_16x16x32_bf16(a1, bf[ct], acc[1][ct], 0, 0, 0);
    }
    __builtin_amdgcn_s_setprio(0);

    if ((s & 7) == 7){                       // tile epilogue (stores stall only this wave)
      const int tile = mg*4 + (s >> 3);
      const int lr0 = wr*32 + q*4;
      const int lc0 = nh*128 + wc*64 + r15;
#pragma unroll
      for (int rt = 0; rt < 2; ++rt)
#pragma unroll
        for (int ct = 0; ct < 4; ++ct){
#pragma unroll
          for (int i = 0; i < 4; ++i){
            size_t grow = (size_t)tile*128 + lr0 + rt*16 + i;
            float v = acc[rt][ct][i];
            C[grow*HD + lc0 + ct*16] = f2bf(v);
            if (grow < NN){ cs[ct] += v; cq[ct] += v*v; }  // mask pad rows from BN stats
          }
          acc[rt][ct] = zz;
        }
    }
  }

  // ---- deferred BN-stat reduce (block covers 128 cols; st zeroed pre-barrier) ----
  const int cl0 = wc*64 + r15;               // column index within this N-half
#pragma unroll
  for (int ct = 0; ct < 4; ++ct){
    float s2 = cs[ct], q2 = cq[ct];
    s2 += __shfl_xor(s2, 16); s2 += __shfl_xor(s2, 32);
    q2 += __shfl_xor(q2, 16); q2 += __shfl_xor(q2, 32);
    if (q == 0){
      atomicAdd(&st[cl0 + ct*16], s2);
      atomicAdd(&st[256 + cl0 + ct*16], q2);
    }
  }
  __syncthreads();
  if (tid < 128){
    atomicAdd(&gsum[nh*128 + tid], st[tid]);
    atomicAdd(&gsq[nh*128 + tid],  st[256 + tid]);
  }
}

__global__ __launch_bounds__(512) void k_gemm(const unsigned short* __restrict__ A,
                                              const unsigned short* __restrict__ B,
                                              unsigned short* __restrict__ C,
                                              float* __restrict__ gsum, float* __restrict__ gsq){
  gemm_body<false>(A, B, C, gsum, gsq, nullptr, nullptr, nullptr, nullptr);
}
__global__ __launch_bounds__(512) void k_gemm2(const unsigned short* __restrict__ T,
                                               const float* __restrict__ sum1,
                                               const float* __restrict__ sq1,
                                               const float* __restrict__ g1v,
                                               const float* __restrict__ be1v,
                                               const unsigned short* __restrict__ B,
                                               unsigned short* __restrict__ C,
                                               float* __restrict__ gsum, float* __restrict__ gsq){
  gemm_body<true>(T, B, C, gsum, gsq, sum1, sq1, g1v, be1v);
}

// ---- fuse: r = h + relu(a*t2+c); h' = LN(r) ----
// per-column BN coefs computed once per block into LDS; cvt_pk packing (R10 win)
// t2 may alias mbf (same-address read-then-write per thread) -> no restrict there
__global__ void k_fuse(const unsigned short* t2,
                       const float* __restrict__ sum, const float* __restrict__ sq,
                       const float* __restrict__ g, const float* __restrict__ be,
                       const float* __restrict__ lg, const float* __restrict__ lb,
                       unsigned short* __restrict__ hbf, unsigned short* mbf,
                       int writem){
  __shared__ float sav[256];
  __shared__ float scv[256];
  const int tid = threadIdx.x;
  {
    const float inv_n = 1.f/(float)NN;
    float sv = sum[tid], qv = sq[tid];
    float mean = sv * inv_n;
    float var  = fmaxf(qv * inv_n - mean*mean, 0.f);
    float a = g[tid] * rsqrtf(var + 1e-5f);
    sav[tid] = a;
    scv[tid] = be[tid] - a*mean;
  }
  __syncthreads();

  int half = tid >> 5, lane32 = tid & 31;
  size_t row = (size_t)blockIdx.x*8 + half;
  int col = lane32 << 3;
  size_t base = row*HD + col;
  uint4 o;
  if (row < NN){
    float4 av0 = *(const float4*)&sav[col], av1 = *(const float4*)&sav[col + 4];
    float4 cv0 = *(const float4*)&scv[col], cv1 = *(const float4*)&scv[col + 4];
    uint4 tv = *(const uint4*)(t2 + base);
    uint4 hv = *(const uint4*)(hbf + base);
    float r0 = bflo(hv.x) + fmaxf(av0.x*bflo(tv.x) + cv0.x, 0.f);
    float r1 = bfhi(hv.x) + fmaxf(av0.y*bfhi(tv.x) + cv0.y, 0.f);
    float r2 = bflo(hv.y) + fmaxf(av0.z*bflo(tv.y) + cv0.z, 0.f);
    float r3 = bfhi(hv.y) + fmaxf(av0.w*bfhi(tv.y) + cv0.w, 0.f);
    float r4 = bflo(hv.z) + fmaxf(av1.x*bflo(tv.z) + cv1.x, 0.f);
    float r5 = bfhi(hv.z) + fmaxf(av1.y*bfhi(tv.z) + cv1.y, 0.f);
    float r6 = bflo(hv.w) + fmaxf(av1.z*bflo(tv.w) + cv1.z, 0.f);
    float r7 = bfhi(hv.w) + fmaxf(av1.w*bfhi(tv.w) + cv1.w, 0.f);
    float s  = r0+r1+r2+r3+r4+r5+r6+r7;
    float qq = r0*r0+r1*r1+r2*r2+r3*r3+r4*r4+r5*r5+r6*r6+r7*r7;
#pragma unroll
    for (int d = 1; d < 32; d <<= 1){ s += __shfl_xor(s, d); qq += __shfl_xor(qq, d); }
    float mean = s * (1.f/256.f);
    float var  = fmaxf(qq * (1.f/256.f) - mean*mean, 0.f);
    float inv  = rsqrtf(var + 1e-5f);
    float4 gv0 = *(const float4*)(lg + col), gv1 = *(const float4*)(lg + col + 4);
    float4 bv0 = *(const float4*)(lb + col), bv1 = *(const float4*)(lb + col + 4);
    o.x = cvtpk(gv0.x*(r0 - mean)*inv + bv0.x, gv0.y*(r1 - mean)*inv + bv0.y);
    o.y = cvtpk(gv0.z*(r2 - mean)*inv + bv0.z, gv0.w*(r3 - mean)*inv + bv0.w);
    o.z = cvtpk(gv1.x*(r4 - mean)*inv + bv1.x, gv1.y*(r5 - mean)*inv + bv1.y);
    o.w = cvtpk(gv1.z*(r6 - mean)*inv + bv1.z, gv1.w*(r7 - mean)*inv + bv1.w);
  } else {
    o.x = o.y = o.z = o.w = 0u;
  }
  *(uint4*)(hbf + base) = o;
  if (writem) *(uint4*)(mbf + base) = o;
}

// ---- readout: out[g,o] = dot(h[root_g], Wout[o]) ; root_g = g*2047 ----
__global__ void k_readout(const unsigned short* __restrict__ hbf, const float* __restrict__ Wo,
                          float* __restrict__ out){
  int g = blockIdx.x;
  int w = threadIdx.x >> 6, lane = threadIdx.x & 63;
  uint2 hv = *(const uint2*)(hbf + (size_t)g*TT*HD + (lane<<2));
  float h0 = bflo(hv.x), h1 = bfhi(hv.x), h2 = bflo(hv.y), h3 = bfhi(hv.y);
#pragma unroll
  for (int oo = 0; oo < 8; ++oo){
    int o = w*8 + oo;
    float4 wv = *(const float4*)(Wo + (size_t)o*HD + (lane<<2));
    float p = h0*wv.x + h1*wv.y + h2*wv.z + h3*wv.w;
#pragma unroll
    for (int d = 1; d < 64; d <<= 1) p += __shfl_xor(p, d);
    if (lane == 0) out[g*32 + o] = p;
  }
}

extern "C" void kernel_launch(void* const* d_in, const int* in_sizes, int n_in,
                              void* d_out, int out_size, void* d_ws, size_t ws_size,
                              hipStream_t stream){
  const int*   x   = (const int*)d_in[0];
  const int*   es  = (const int*)d_in[1];
  const int*   ed  = (const int*)d_in[2];
  const float* ew  = (const float*)d_in[3];
  // d_in[4] batch, d_in[5] root_index: structural (i/2047, g*2047) -> unused
  const float* en  = (const float*)d_in[6];
  const float* el  = (const float*)d_in[7];
  const float* W1  = (const float*)d_in[8];
  // d_in[9] b1, d_in[13] b2: per-column bias cancels through batch-norm -> unused
  const float* g1  = (const float*)d_in[10];
  const float* be1 = (const float*)d_in[11];
  const float* W2  = (const float*)d_in[12];
  const float* g2  = (const float*)d_in[14];
  const float* be2 = (const float*)d_in[15];
  const float* lg  = (const float*)d_in[16];
  const float* lb  = (const float*)d_in[17];
  const float* Wo  = (const float*)d_in[18];

  // workspace layout (~206.1 MB total; proven in rounds 2-13):
  char* ws = (char*)d_ws;
  unsigned short* hbf = (unsigned short*)ws;                     // 67,108,864 B  h (bf16)
  unsigned short* mbf = (unsigned short*)(ws + 67108864);        // 67,108,864 B  m / gemm2-out (bf16)
  unsigned short* t   = (unsigned short*)(ws + 134217728);       // 67,108,864 B  gemm1 out (bf16)
  unsigned short* wbf = (unsigned short*)(ws + 201326592);       // 1,048,576 B   W1|W2 (bf16)
  float* stats   = (float*)(ws + 202375168);                     // 16,384 B (8 layers x 512)
  int*   deg     = (int*)  (ws + 202391552);                     // 524,288 B
  int*   cursor0 = (int*)  (ws + 202915840);                     // 524,288 B (zeroed; fill slots)
  int*   start   = (int*)  (ws + 203440128);                     // 524,288 B (block-local scan)
  int*   bsum    = (int*)  (ws + 203964416);                     // 4,096 B
  uint2* pairs   = (uint2*)(ws + 203968512);                     // 2,096,128 B

  // one memset covers stats + deg + cursor0 (contiguous)
  hipMemsetAsync(stats, 0, 16384 + 524288 + 524288, stream);
  // prep: convw | embed | hist in one dispatch
  k_prep<<<19456, 256, 0, stream>>>(W1, W2, wbf, x, en, el, hbf, ed, deg);

  // CSR build: scan_block -> scan_top -> fill (initcur folded into fill)
  k_scan_block<<<512, 256, 0, stream>>>(deg, start, bsum);
  k_scan_top  <<<1,   512, 0, stream>>>(bsum);
  k_fill      <<<1024,256, 0, stream>>>(es, ed, ew, start, bsum, cursor0, pairs);

  for (int i = 0; i < 4; ++i){
    float* s1 = stats + (2*i)*512;
    float* s2 = stats + (2*i+1)*512;
    if (i < 3) k_gather <<<16384, 256, 0, stream>>>(deg, start, bsum, pairs, hbf, mbf);
    else       k_rootsum<<<1024,  128, 0, stream>>>(hbf, mbf);

    // gemm1: t = m @ W1^T, stats -> s1 (N-split, 512 blocks, 2/CU)
    k_gemm <<<512, 512, 0, stream>>>(mbf, wbf + i*65536, t, s1, s1 + 256);
    // gemm2: mbf = relu(bn1(t)) @ W2^T (bn1+relu in-register, cvt_pk rounding)
    k_gemm2<<<512, 512, 0, stream>>>(t, s1, s1 + 256, g1 + i*256, be1 + i*256,
                                     wbf + 262144 + i*65536, mbf, s2, s2 + 256);
    // fuse: h = LN(h + relu(bn2(mbf))); writes mbf too on i==2 (rootsum init)
    k_fuse <<<16384, 256, 0, stream>>>(mbf, s2, s2 + 256, g2 + i*256, be2 + i*256,
                                       lg + i*256, lb + i*256, hbf, mbf, (i == 2) ? 1 : 0);
  }

  k_readout<<<64, 256, 0, stream>>>(hbf, Wo, (float*)d_out);
  (void)in_sizes; (void)n_in; (void)out_size; (void)ws_size;
}

// Round 13
// 717.019 us; speedup vs baseline: 1.0988x; 1.0988x over previous
//
#include <hip/hip_runtime.h>
#include <stdint.h>

#define NN 131008      // real node count
#define NPAD 131072    // padded to 1024 * 128
#define EE 262016
#define HD 256
#define GG 64
#define TT 2047

typedef __attribute__((ext_vector_type(8))) short bfrag;
typedef __attribute__((ext_vector_type(4))) float f32x4;

__device__ __forceinline__ float bflo(unsigned u){ union{unsigned i; float f;} v; v.i = u<<16; return v.f; }
__device__ __forceinline__ float bfhi(unsigned u){ union{unsigned i; float f;} v; v.i = u & 0xffff0000u; return v.f; }
__device__ __forceinline__ unsigned short f2bf(float f){
  union{unsigned i; float fl;} v; v.fl = f; unsigned i = v.i;
  return (unsigned short)((i + 0x7fffu + ((i>>16)&1u)) >> 16);
}
__device__ __forceinline__ unsigned pack2(float a, float b){
  return (unsigned)f2bf(a) | ((unsigned)f2bf(b)<<16);
}
// HW packed f32->bf16 RNE (identical rounding to f2bf; 1 op per pair vs ~11)
__device__ __forceinline__ unsigned cvtpk(float a, float b){
  unsigned r; asm("v_cvt_pk_bf16_f32 %0, %1, %2" : "=v"(r) : "v"(a), "v"(b)); return r;
}
__device__ __forceinline__ float bfel(short s){
  union{unsigned i; float f;} v; v.i = ((unsigned)(unsigned short)s) << 16; return v.f;
}
__device__ __forceinline__ void gload16(const void* g, void* s){
  __builtin_amdgcn_global_load_lds((__attribute__((address_space(1))) void*)g,
                                   (__attribute__((address_space(3))) void*)s, 16, 0, 0);
}

// bn+relu on 8 bf16 values; rounds back to bf16 via cvt_pk pairs
__device__ __forceinline__ bfrag bnrelu8(bfrag t, float4 a0, float4 a1, float4 c0, float4 c1){
  unsigned u0 = cvtpk(fmaxf(a0.x*bfel(t[0])+c0.x,0.f), fmaxf(a0.y*bfel(t[1])+c0.y,0.f));
  unsigned u1 = cvtpk(fmaxf(a0.z*bfel(t[2])+c0.z,0.f), fmaxf(a0.w*bfel(t[3])+c0.w,0.f));
  unsigned u2 = cvtpk(fmaxf(a1.x*bfel(t[4])+c1.x,0.f), fmaxf(a1.y*bfel(t[5])+c1.y,0.f));
  unsigned u3 = cvtpk(fmaxf(a1.z*bfel(t[6])+c1.z,0.f), fmaxf(a1.w*bfel(t[7])+c1.w,0.f));
  union{ unsigned u[4]; bfrag b; } r;
  r.u[0]=u0; r.u[1]=u1; r.u[2]=u2; r.u[3]=u3;
  return r.b;
}

// atomic add of two bf16 values at a 4B-aligned pair address (rootsum only)
__device__ __forceinline__ void atomic_add_bf16x2(unsigned short* p, float a, float b){
#if __has_builtin(__builtin_amdgcn_global_atomic_fadd_v2bf16)
  typedef __attribute__((ext_vector_type(2))) short s16x2;
  s16x2 v; v.x = (short)f2bf(a); v.y = (short)f2bf(b);
  __builtin_amdgcn_global_atomic_fadd_v2bf16((__attribute__((address_space(1))) s16x2*)p, v);
#else
  unsigned* up = (unsigned*)p;
  unsigned old = *up, assumed;
  do {
    assumed = old;
    unsigned nv = pack2(bflo(assumed) + a, bfhi(assumed) + b);
    old = atomicCAS(up, assumed, nv);
  } while (old != assumed);
#endif
}

// ---- prep: convw (blocks 0..2047) | embed (2048..18431) | hist (18432..19455) ----
__global__ void k_prep(const float* __restrict__ W1, const float* __restrict__ W2,
                       unsigned short* __restrict__ wbf,
                       const int* __restrict__ x, const float* __restrict__ en,
                       const float* __restrict__ el, unsigned short* __restrict__ hbf,
                       const int* __restrict__ ed, int* __restrict__ deg){
  int b = blockIdx.x;
  if (b < 2048){                    // convw: 524288 floats -> bf16
    int idx = b*256 + threadIdx.x;
    float v = (idx < 262144) ? W1[idx] : W2[idx - 262144];
    wbf[idx] = f2bf(v);
  } else if (b < 18432){            // embed: 8 cols/thread
    size_t i8 = ((size_t)(b - 2048)*256 + threadIdx.x) << 3;
    int row = (int)(i8 >> 8); int k = (int)(i8 & 255);
    uint4 o;
    if (row < NN){
      const float* src = (k < 128) ? en + (size_t)x[2*row]*128 + k
                                   : el + (size_t)x[2*row+1]*128 + (k-128);
      float4 v0 = *(const float4*)src;
      float4 v1 = *(const float4*)(src + 4);
      o.x = cvtpk(v0.x, v0.y); o.y = cvtpk(v0.z, v0.w);
      o.z = cvtpk(v1.x, v1.y); o.w = cvtpk(v1.z, v1.w);
    } else { o.x = o.y = o.z = o.w = 0u; }
    *(uint4*)(hbf + i8) = o;
  } else {                          // hist
    int e = (b - 18432)*256 + threadIdx.x;
    if (e < EE) atomicAdd(&deg[ed[e]], 1);
  }
}

// ======== CSR build (edges fixed; rebuilt every launch) ========
__global__ void k_scan_block(const int* __restrict__ deg, int* __restrict__ start,
                             int* __restrict__ bsum){
  __shared__ int sh[256];
  int t = threadIdx.x;
  int i = blockIdx.x*256 + t;
  int v = deg[i];
  int val = v; sh[t] = val; __syncthreads();
  for (int off = 1; off < 256; off <<= 1){
    int add = (t >= off) ? sh[t-off] : 0;
    __syncthreads();
    val += add; sh[t] = val;
    __syncthreads();
  }
  start[i] = val - v;
  if (t == 255) bsum[blockIdx.x] = val;
}
__global__ void k_scan_top(int* __restrict__ bsum){
  __shared__ int sh[512];
  int t = threadIdx.x;            // 512 threads
  int v = bsum[t];
  int val = v; sh[t] = val; __syncthreads();
  for (int off = 1; off < 512; off <<= 1){
    int add = (t >= off) ? sh[t-off] : 0;
    __syncthreads();
    val += add; sh[t] = val;
    __syncthreads();
  }
  bsum[t] = val - v;
}
__global__ void k_fill(const int* __restrict__ es, const int* __restrict__ ed,
                       const float* __restrict__ ew, const int* __restrict__ start,
                       const int* __restrict__ bsum,
                       int* __restrict__ cursor0, uint2* __restrict__ pairs){
  int e = blockIdx.x*256 + threadIdx.x;
  if (e < EE){
    int d = ed[e];
    int pos = start[d] + bsum[d >> 8] + atomicAdd(&cursor0[d], 1);
    uint2 p; p.x = (unsigned)es[e];
    union{float f; unsigned u;} w; w.f = ew[e];
    p.y = w.u;
    pairs[pos] = p;
  }
}

// ---- gather: m[r] = h[r] + sum_{e:dst=r} w_e*h[src_e] ----
// 32 lanes/row x 8 cols (uint4); 8 rows/block; edge loop unrolled x2 so the two
// dependent load chains (pairs -> h[src]) overlap.
__global__ void k_gather(const int* __restrict__ deg, const int* __restrict__ start,
                         const int* __restrict__ bsum,
                         const uint2* __restrict__ pairs,
                         const unsigned short* __restrict__ hbf,
                         unsigned short* __restrict__ mbf){
  int half = threadIdx.x >> 5, lane32 = threadIdx.x & 31;
  int row = blockIdx.x*8 + half;
  size_t base = (size_t)row*HD + (lane32 << 3);
  uint4 o;
  if (row < NN){
    uint4 hv = *(const uint4*)(hbf + base);
    float a0 = bflo(hv.x), a1 = bfhi(hv.x), a2 = bflo(hv.y), a3 = bfhi(hv.y);
    float a4 = bflo(hv.z), a5 = bfhi(hv.z), a6 = bflo(hv.w), a7 = bfhi(hv.w);
    int d = deg[row], s = start[row] + bsum[row >> 8];
    int j = 0;
    for (; j + 2 <= d; j += 2){
      uint2 p0 = pairs[s + j];
      uint2 p1 = pairs[s + j + 1];
      union{unsigned u; float f;} w0; w0.u = p0.y;
      union{unsigned u; float f;} w1; w1.u = p1.y;
      uint4 s0 = *(const uint4*)(hbf + (size_t)p0.x*HD + (lane32 << 3));
      uint4 s1 = *(const uint4*)(hbf + (size_t)p1.x*HD + (lane32 << 3));
      a0 += bflo(s0.x)*w0.f + bflo(s1.x)*w1.f; a1 += bfhi(s0.x)*w0.f + bfhi(s1.x)*w1.f;
      a2 += bflo(s0.y)*w0.f + bflo(s1.y)*w1.f; a3 += bfhi(s0.y)*w0.f + bfhi(s1.y)*w1.f;
      a4 += bflo(s0.z)*w0.f + bflo(s1.z)*w1.f; a5 += bfhi(s0.z)*w0.f + bfhi(s1.z)*w1.f;
      a6 += bflo(s0.w)*w0.f + bflo(s1.w)*w1.f; a7 += bfhi(s0.w)*w0.f + bfhi(s1.w)*w1.f;
    }
    if (j < d){
      uint2 pr = pairs[s + j];
      union{unsigned u; float f;} wg; wg.u = pr.y;
      uint4 sv = *(const uint4*)(hbf + (size_t)pr.x*HD + (lane32 << 3));
      a0 += bflo(sv.x)*wg.f; a1 += bfhi(sv.x)*wg.f;
      a2 += bflo(sv.y)*wg.f; a3 += bfhi(sv.y)*wg.f;
      a4 += bflo(sv.z)*wg.f; a5 += bfhi(sv.z)*wg.f;
      a6 += bflo(sv.w)*wg.f; a7 += bfhi(sv.w)*wg.f;
    }
    o.x = cvtpk(a0, a1); o.y = cvtpk(a2, a3);
    o.z = cvtpk(a4, a5); o.w = cvtpk(a6, a7);
  } else { o.x = o.y = o.z = o.w = 0u; }
  *(uint4*)(mbf + base) = o;
}

// ---- last layer: m[root_g] += sum of h over graph g's 2047 contiguous rows ----
__global__ void k_rootsum(const unsigned short* __restrict__ hbf, unsigned short* __restrict__ m){
  int g = blockIdx.x >> 4, ch = blockIdx.x & 15;
  int col = threadIdx.x * 2;
  int nr = (ch == 15) ? 127 : 128;
  const unsigned short* p = hbf + ((size_t)g*TT + ch*128)*HD + col;
  float a = 0.f, b = 0.f;
  for (int r = 0; r < nr; ++r){
    unsigned u = *(const unsigned*)(p + (size_t)r*HD);
    a += bflo(u); b += bfhi(u);
  }
  atomic_add_bf16x2(m + (size_t)g*TT*HD + col, a, b);
}

// ======== Persistent GEMM (round-24 = R12 resubmit; R12 died to infra) ========
// R11 N-split regressed (41.4->50.9us): 2x A fetch + 2x bn1 VALU ate the
// occupancy gain -> reverted to R10 full-N. R10 PMC (VALU 32 / MFMA 15 /
// HBM 30, nothing saturated) = exposed A-load latency at 1 block/CU with
// distance-3 ring (~750cy cover vs ~600-900cy L3/HBM). Fix: ring depth 8,
// prefetch distance 6 (~1500cy cover). Work-neutral: +64 VGPR (~160 total,
// budget 256 at 1 block/CU). Nothing here can hang: no grid sync, no spins.
template<bool TRANS>
__device__ __forceinline__ void gemm_body(const unsigned short* __restrict__ A,
                                          const unsigned short* __restrict__ B,
                                          unsigned short* __restrict__ C,
                                          float* __restrict__ gsum, float* __restrict__ gsq,
                                          const float* __restrict__ sum1,
                                          const float* __restrict__ sq1,
                                          const float* __restrict__ g1v,
                                          const float* __restrict__ be1v){
  __shared__ unsigned short Bs[65536];      // 128 KB: 4 kt-blocks of [256][64], XOR-swizzled
  __shared__ float st[512];                 // end-of-block stat scratch
  __shared__ float acf[256];                // gemm2 BN coefs (a)
  __shared__ float ccf[256];                // gemm2 BN coefs (c)
  const int tid = threadIdx.x, lane = tid & 63, w = tid >> 6;   // 8 waves
  const int wr = w >> 1, wc = w & 1;        // 4 x 2 wave grid; wave tile 32x128
  const int b = blockIdx.x;                 // 0..255
  const int q = lane >> 4, r15 = lane & 15, r7 = lane & 7;

  if (TRANS && tid < 256){
    const float inv_n = 1.f/(float)NN;
    float mean = sum1[tid] * inv_n;
    float var  = fmaxf(sq1[tid] * inv_n - mean*mean, 0.f);
    float aj   = g1v[tid] * rsqrtf(var + 1e-5f);
    acf[tid] = aj;
    ccf[tid] = be1v[tid] - aj*mean;
  }
  st[tid < 512 ? tid : 0] = 0.f;

  // stage ALL of B once (16 DMAs/thread)
#pragma unroll
  for (int kt = 0; kt < 4; ++kt)
#pragma unroll
    for (int it = 0; it < 4; ++it){
      int ci = it*512 + tid;
      int row = ci >> 3, cp = ci & 7;
      int cl = cp ^ (row & 7);
      gload16(B + (size_t)row*HD + kt*64 + cl*8, &Bs[kt*16384 + ci*8]);
    }

  // A register ring, depth 8 (slot s&7; prefetch distance 6 ~ 1500cy cover)
  bfrag rA[8][2];
  auto aload = [&](int s, int slot){
    const int t2 = b*4 + (s >> 3), ks = s & 7;
    const unsigned short* p = A + ((size_t)(t2*128 + wr*32 + r15))*HD + ks*32 + (q << 3);
    rA[slot][0] = *(const bfrag*)p;
    rA[slot][1] = *(const bfrag*)(p + 16*HD);
  };
#pragma unroll
  for (int s0 = 0; s0 < 6; ++s0) aload(s0, s0);

  asm volatile("s_waitcnt vmcnt(0) lgkmcnt(0)" ::: "memory");
  __builtin_amdgcn_s_barrier();             // the ONLY block barrier before the reduce

  f32x4 acc[2][8];
  f32x4 zz = {0.f, 0.f, 0.f, 0.f};
#pragma unroll
  for (int a = 0; a < 2; ++a)
#pragma unroll
    for (int c = 0; c < 8; ++c) acc[a][c] = zz;
  float cs[8] = {0,0,0,0,0,0,0,0}, cq[8] = {0,0,0,0,0,0,0,0};

#pragma unroll 8
  for (int s = 0; s < 32; ++s){
    if (s < 26) aload(s + 6, (s + 6) & 7);  // per-wave prefetch, distance 6

    bfrag a0 = rA[s & 7][0], a1 = rA[s & 7][1];
    const int ks = s & 7;
    if (TRANS){
      const int kb = ks*32 + (q << 3);
      float4 ca0 = *(const float4*)&acf[kb];
      float4 ca1 = *(const float4*)&acf[kb + 4];
      float4 cc0 = *(const float4*)&ccf[kb];
      float4 cc1 = *(const float4*)&ccf[kb + 4];
      a0 = bnrelu8(a0, ca0, ca1, cc0, cc1);
      a1 = bnrelu8(a1, ca0, ca1, cc0, cc1);
    }

    const int kt64 = ks >> 1, hf = ks & 1;
    bfrag bf[8];
#pragma unroll
    for (int ct = 0; ct < 8; ++ct){
      int rb = wc*128 + ct*16 + r15;
      bf[ct] = *(const bfrag*)&Bs[kt64*16384 + rb*64 + (((q + 4*hf) ^ r7) << 3)];
    }
    __builtin_amdgcn_s_setprio(1);
#pragma unroll
    for (int ct = 0; ct < 8; ++ct){
      acc[0][ct] = __builtin_amdgcn_mfma_f32_16x16x32_bf16(a0, bf[ct], acc[0][ct], 0, 0, 0);
      acc[1][ct] = __builtin_amdgcn_mfma_f32_16x16x32_bf16(a1, bf[ct], acc[1][ct], 0, 0, 0);
    }
    __builtin_amdgcn_s_setprio(0);

    if ((s & 7) == 7){                       // tile epilogue (stores stall only this wave)
      const int tile = b*4 + (s >> 3);
      const int lr0 = wr*32 + q*4;
      const int lc0 = wc*128 + r15;
#pragma unroll
      for (int rt = 0; rt < 2; ++rt)
#pragma unroll
        for (int ct = 0; ct < 8; ++ct){
#pragma unroll
          for (int i = 0; i < 4; ++i){
            size_t grow = (size_t)tile*128 + lr0 + rt*16 + i;
            float v = acc[rt][ct][i];
            C[grow*HD + lc0 + ct*16] = f2bf(v);
            if (grow < NN){ cs[ct] += v; cq[ct] += v*v; }  // mask pad rows from BN stats
          }
          acc[rt][ct] = zz;
        }
    }
  }

  // ---- deferred BN-stat reduce (st zeroed before the prologue barrier) ----
  const int lc0 = wc*128 + r15;
#pragma unroll
  for (int ct = 0; ct < 8; ++ct){
    float s2 = cs[ct], q2 = cq[ct];
    s2 += __shfl_xor(s2, 16); s2 += __shfl_xor(s2, 32);
    q2 += __shfl_xor(q2, 16); q2 += __shfl_xor(q2, 32);
    if (q == 0){
      atomicAdd(&st[lc0 + ct*16], s2);
      atomicAdd(&st[256 + lc0 + ct*16], q2);
    }
  }
  __syncthreads();
  if (tid < 256){
    atomicAdd(&gsum[tid], st[tid]);
    atomicAdd(&gsq[tid], st[256 + tid]);
  }
}

__global__ __launch_bounds__(512) void k_gemm(const unsigned short* __restrict__ A,
                                              const unsigned short* __restrict__ B,
                                              unsigned short* __restrict__ C,
                                              float* __restrict__ gsum, float* __restrict__ gsq){
  gemm_body<false>(A, B, C, gsum, gsq, nullptr, nullptr, nullptr, nullptr);
}
__global__ __launch_bounds__(512) void k_gemm2(const unsigned short* __restrict__ T,
                                               const float* __restrict__ sum1,
                                               const float* __restrict__ sq1,
                                               const float* __restrict__ g1v,
                                               const float* __restrict__ be1v,
                                               const unsigned short* __restrict__ B,
                                               unsigned short* __restrict__ C,
                                               float* __restrict__ gsum, float* __restrict__ gsq){
  gemm_body<true>(T, B, C, gsum, gsq, sum1, sq1, g1v, be1v);
}

// ---- fuse: r = h + relu(a*t2+c); h' = LN(r) ----
// per-column BN coefs computed once per block into LDS; cvt_pk packing (R10 win)
// t2 may alias mbf (same-address read-then-write per thread) -> no restrict there
__global__ void k_fuse(const unsigned short* t2,
                       const float* __restrict__ sum, const float* __restrict__ sq,
                       const float* __restrict__ g, const float* __restrict__ be,
                       const float* __restrict__ lg, const float* __restrict__ lb,
                       unsigned short* __restrict__ hbf, unsigned short* mbf,
                       int writem){
  __shared__ float sav[256];
  __shared__ float scv[256];
  const int tid = threadIdx.x;
  {
    const float inv_n = 1.f/(float)NN;
    float sv = sum[tid], qv = sq[tid];
    float mean = sv * inv_n;
    float var  = fmaxf(qv * inv_n - mean*mean, 0.f);
    float a = g[tid] * rsqrtf(var + 1e-5f);
    sav[tid] = a;
    scv[tid] = be[tid] - a*mean;
  }
  __syncthreads();

  int half = tid >> 5, lane32 = tid & 31;
  size_t row = (size_t)blockIdx.x*8 + half;
  int col = lane32 << 3;
  size_t base = row*HD + col;
  uint4 o;
  if (row < NN){
    float4 av0 = *(const float4*)&sav[col], av1 = *(const float4*)&sav[col + 4];
    float4 cv0 = *(const float4*)&scv[col], cv1 = *(const float4*)&scv[col + 4];
    uint4 tv = *(const uint4*)(t2 + base);
    uint4 hv = *(const uint4*)(hbf + base);
    float r0 = bflo(hv.x) + fmaxf(av0.x*bflo(tv.x) + cv0.x, 0.f);
    float r1 = bfhi(hv.x) + fmaxf(av0.y*bfhi(tv.x) + cv0.y, 0.f);
    float r2 = bflo(hv.y) + fmaxf(av0.z*bflo(tv.y) + cv0.z, 0.f);
    float r3 = bfhi(hv.y) + fmaxf(av0.w*bfhi(tv.y) + cv0.w, 0.f);
    float r4 = bflo(hv.z) + fmaxf(av1.x*bflo(tv.z) + cv1.x, 0.f);
    float r5 = bfhi(hv.z) + fmaxf(av1.y*bfhi(tv.z) + cv1.y, 0.f);
    float r6 = bflo(hv.w) + fmaxf(av1.z*bflo(tv.w) + cv1.z, 0.f);
    float r7 = bfhi(hv.w) + fmaxf(av1.w*bfhi(tv.w) + cv1.w, 0.f);
    float s  = r0+r1+r2+r3+r4+r5+r6+r7;
    float qq = r0*r0+r1*r1+r2*r2+r3*r3+r4*r4+r5*r5+r6*r6+r7*r7;
#pragma unroll
    for (int d = 1; d < 32; d <<= 1){ s += __shfl_xor(s, d); qq += __shfl_xor(qq, d); }
    float mean = s * (1.f/256.f);
    float var  = fmaxf(qq * (1.f/256.f) - mean*mean, 0.f);
    float inv  = rsqrtf(var + 1e-5f);
    float4 gv0 = *(const float4*)(lg + col), gv1 = *(const float4*)(lg + col + 4);
    float4 bv0 = *(const float4*)(lb + col), bv1 = *(const float4*)(lb + col + 4);
    o.x = cvtpk(gv0.x*(r0 - mean)*inv + bv0.x, gv0.y*(r1 - mean)*inv + bv0.y);
    o.y = cvtpk(gv0.z*(r2 - mean)*inv + bv0.z, gv0.w*(r3 - mean)*inv + bv0.w);
    o.z = cvtpk(gv1.x*(r4 - mean)*inv + bv1.x, gv1.y*(r5 - mean)*inv + bv1.y);
    o.w = cvtpk(gv1.z*(r6 - mean)*inv + bv1.z, gv1.w*(r7 - mean)*inv + bv1.w);
  } else {
    o.x = o.y = o.z = o.w = 0u;
  }
  *(uint4*)(hbf + base) = o;
  if (writem) *(uint4*)(mbf + base) = o;
}

// ---- readout: out[g,o] = dot(h[root_g], Wout[o]) ; root_g = g*2047 ----
__global__ void k_readout(const unsigned short* __restrict__ hbf, const float* __restrict__ Wo,
                          float* __restrict__ out){
  int g = blockIdx.x;
  int w = threadIdx.x >> 6, lane = threadIdx.x & 63;
  uint2 hv = *(const uint2*)(hbf + (size_t)g*TT*HD + (lane<<2));
  float h0 = bflo(hv.x), h1 = bfhi(hv.x), h2 = bflo(hv.y), h3 = bfhi(hv.y);
#pragma unroll
  for (int oo = 0; oo < 8; ++oo){
    int o = w*8 + oo;
    float4 wv = *(const float4*)(Wo + (size_t)o*HD + (lane<<2));
    float p = h0*wv.x + h1*wv.y + h2*wv.z + h3*wv.w;
#pragma unroll
    for (int d = 1; d < 64; d <<= 1) p += __shfl_xor(p, d);
    if (lane == 0) out[g*32 + o] = p;
  }
}

extern "C" void kernel_launch(void* const* d_in, const int* in_sizes, int n_in,
                              void* d_out, int out_size, void* d_ws, size_t ws_size,
                              hipStream_t stream){
  const int*   x   = (const int*)d_in[0];
  const int*   es  = (const int*)d_in[1];
  const int*   ed  = (const int*)d_in[2];
  const float* ew  = (const float*)d_in[3];
  // d_in[4] batch, d_in[5] root_index: structural (i/2047, g*2047) -> unused
  const float* en  = (const float*)d_in[6];
  const float* el  = (const float*)d_in[7];
  const float* W1  = (const float*)d_in[8];
  // d_in[9] b1, d_in[13] b2: per-column bias cancels through batch-norm -> unused
  const float* g1  = (const float*)d_in[10];
  const float* be1 = (const float*)d_in[11];
  const float* W2  = (const float*)d_in[12];
  const float* g2  = (const float*)d_in[14];
  const float* be2 = (const float*)d_in[15];
  const float* lg  = (const float*)d_in[16];
  const float* lb  = (const float*)d_in[17];
  const float* Wo  = (const float*)d_in[18];

  // workspace layout (~206.1 MB total; proven in rounds 2-13):
  char* ws = (char*)d_ws;
  unsigned short* hbf = (unsigned short*)ws;                     // 67,108,864 B  h (bf16)
  unsigned short* mbf = (unsigned short*)(ws + 67108864);        // 67,108,864 B  m / gemm2-out (bf16)
  unsigned short* t   = (unsigned short*)(ws + 134217728);       // 67,108,864 B  gemm1 out (bf16)
  unsigned short* wbf = (unsigned short*)(ws + 201326592);       // 1,048,576 B   W1|W2 (bf16)
  float* stats   = (float*)(ws + 202375168);                     // 16,384 B (8 layers x 512)
  int*   deg     = (int*)  (ws + 202391552);                     // 524,288 B
  int*   cursor0 = (int*)  (ws + 202915840);                     // 524,288 B (zeroed; fill slots)
  int*   start   = (int*)  (ws + 203440128);                     // 524,288 B (block-local scan)
  int*   bsum    = (int*)  (ws + 203964416);                     // 4,096 B
  uint2* pairs   = (uint2*)(ws + 203968512);                     // 2,096,128 B

  // one memset covers stats + deg + cursor0 (contiguous)
  hipMemsetAsync(stats, 0, 16384 + 524288 + 524288, stream);
  // prep: convw | embed | hist in one dispatch
  k_prep<<<19456, 256, 0, stream>>>(W1, W2, wbf, x, en, el, hbf, ed, deg);

  // CSR build: scan_block -> scan_top -> fill (initcur folded into fill)
  k_scan_block<<<512, 256, 0, stream>>>(deg, start, bsum);
  k_scan_top  <<<1,   512, 0, stream>>>(bsum);
  k_fill      <<<1024,256, 0, stream>>>(es, ed, ew, start, bsum, cursor0, pairs);

  for (int i = 0; i < 4; ++i){
    float* s1 = stats + (2*i)*512;
    float* s2 = stats + (2*i+1)*512;
    if (i < 3) k_gather <<<16384, 256, 0, stream>>>(deg, start, bsum, pairs, hbf, mbf);
    else       k_rootsum<<<1024,  128, 0, stream>>>(hbf, mbf);

    // gemm1: t = m @ W1^T, stats -> s1 (persistent, 256 blocks, deep A-ring)
    k_gemm <<<256, 512, 0, stream>>>(mbf, wbf + i*65536, t, s1, s1 + 256);
    // gemm2: mbf = relu(bn1(t)) @ W2^T (bn1+relu in-register, cvt_pk rounding)
    k_gemm2<<<256, 512, 0, stream>>>(t, s1, s1 + 256, g1 + i*256, be1 + i*256,
                                     wbf + 262144 + i*65536, mbf, s2, s2 + 256);
    // fuse: h = LN(h + relu(bn2(mbf))); writes mbf too on i==2 (rootsum init)
    k_fuse <<<16384, 256, 0, stream>>>(mbf, s2, s2 + 256, g2 + i*256, be2 + i*256,
                                       lg + i*256, lb + i*256, hbf, mbf, (i == 2) ? 1 : 0);
  }

  k_readout<<<64, 256, 0, stream>>>(hbf, Wo, (float*)d_out);
  (void)in_sizes; (void)n_in; (void)out_size; (void)ws_size;
}